// Round 1
// baseline (2999.332 us; speedup 1.0000x reference)
//
#include <hip/hip_runtime.h>
#include <math.h>

// Problem constants
#define BATCH   2
#define LSEQ    1024
#define DMODEL  1024
#define DSTATE  16
#define DCONV   4
#define DINNER  2048   // EXPAND * DMODEL
#define NROWS   (BATCH * LSEQ)   // 2048

#define TILE 64
#define KT   16
#define LDP  68   // padded LDS leading dim (16B aligned, avoids pow2 conflicts)

// ---------------------------------------------------------------------------
// Generic fp32 GEMM: C[m,n] = sum_k A[m*lda+k] * B[k*ldb+n]
// 64x64 tile, 256 threads, 4x4 micro-tile per thread, K-step 16.
// ---------------------------------------------------------------------------
__global__ __launch_bounds__(256) void gemm_nn(
    const float* __restrict__ A, int lda,
    const float* __restrict__ Bm, int ldb,
    float* __restrict__ C, int ldc,
    int M, int N, int K) {
  __shared__ float As[KT * LDP];  // As[k][m] (transposed for contiguous m reads)
  __shared__ float Bs[KT * LDP];  // Bs[k][n]
  const int tid = threadIdx.x;
  const int tx = tid & 15;   // n-group
  const int ty = tid >> 4;   // m-group
  const int row0 = blockIdx.y * TILE;
  const int col0 = blockIdx.x * TILE;
  float acc[4][4] = {};
  for (int k0 = 0; k0 < K; k0 += KT) {
#pragma unroll
    for (int i = 0; i < 4; ++i) {
      int e = tid + i * 256;
      int m = e >> 4;       // 0..63
      int k = e & 15;       // 0..15
      int gm = row0 + m, gk = k0 + k;
      float v = (gm < M && gk < K) ? A[(size_t)gm * lda + gk] : 0.f;
      As[k * LDP + m] = v;
    }
#pragma unroll
    for (int i = 0; i < 4; ++i) {
      int e = tid + i * 256;
      int k = e >> 6;       // 0..15
      int n = e & 63;       // 0..63
      int gk = k0 + k, gn = col0 + n;
      float v = (gk < K && gn < N) ? Bm[(size_t)gk * ldb + gn] : 0.f;
      Bs[k * LDP + n] = v;
    }
    __syncthreads();
#pragma unroll
    for (int kk = 0; kk < KT; ++kk) {
      float a[4], b[4];
#pragma unroll
      for (int i = 0; i < 4; ++i) a[i] = As[kk * LDP + ty * 4 + i];
#pragma unroll
      for (int j = 0; j < 4; ++j) b[j] = Bs[kk * LDP + tx * 4 + j];
#pragma unroll
      for (int i = 0; i < 4; ++i)
#pragma unroll
        for (int j = 0; j < 4; ++j)
          acc[i][j] += a[i] * b[j];
    }
    __syncthreads();
  }
#pragma unroll
  for (int i = 0; i < 4; ++i) {
    int gm = row0 + ty * 4 + i;
    if (gm >= M) continue;
#pragma unroll
    for (int j = 0; j < 4; ++j) {
      int gn = col0 + tx * 4 + j;
      if (gn < N) C[(size_t)gm * ldc + gn] = acc[i][j];
    }
  }
}

// ---------------------------------------------------------------------------
// GEMM NT: C[m,n] = sum_k A[m*lda+k] * Bt[n*ldb+k]   (B given transposed)
// ---------------------------------------------------------------------------
__global__ __launch_bounds__(256) void gemm_nt(
    const float* __restrict__ A, int lda,
    const float* __restrict__ Bt, int ldb,
    float* __restrict__ C, int ldc,
    int M, int N, int K) {
  __shared__ float As[KT * LDP];
  __shared__ float Bs[KT * LDP];
  const int tid = threadIdx.x;
  const int tx = tid & 15;
  const int ty = tid >> 4;
  const int row0 = blockIdx.y * TILE;
  const int col0 = blockIdx.x * TILE;
  float acc[4][4] = {};
  for (int k0 = 0; k0 < K; k0 += KT) {
#pragma unroll
    for (int i = 0; i < 4; ++i) {
      int e = tid + i * 256;
      int m = e >> 4;
      int k = e & 15;
      int gm = row0 + m, gk = k0 + k;
      float v = (gm < M && gk < K) ? A[(size_t)gm * lda + gk] : 0.f;
      As[k * LDP + m] = v;
    }
#pragma unroll
    for (int i = 0; i < 4; ++i) {
      int e = tid + i * 256;
      int n = e >> 4;       // 0..63
      int k = e & 15;       // 0..15
      int gn = col0 + n, gk = k0 + k;
      float v = (gn < N && gk < K) ? Bt[(size_t)gn * ldb + gk] : 0.f;
      Bs[k * LDP + n] = v;
    }
    __syncthreads();
#pragma unroll
    for (int kk = 0; kk < KT; ++kk) {
      float a[4], b[4];
#pragma unroll
      for (int i = 0; i < 4; ++i) a[i] = As[kk * LDP + ty * 4 + i];
#pragma unroll
      for (int j = 0; j < 4; ++j) b[j] = Bs[kk * LDP + tx * 4 + j];
#pragma unroll
      for (int i = 0; i < 4; ++i)
#pragma unroll
        for (int j = 0; j < 4; ++j)
          acc[i][j] += a[i] * b[j];
    }
    __syncthreads();
  }
#pragma unroll
  for (int i = 0; i < 4; ++i) {
    int gm = row0 + ty * 4 + i;
    if (gm >= M) continue;
#pragma unroll
    for (int j = 0; j < 4; ++j) {
      int gn = col0 + tx * 4 + j;
      if (gn < N) C[(size_t)gm * ldc + gn] = acc[i][j];
    }
  }
}

// ---------------------------------------------------------------------------
// Depthwise causal conv (width 4) + bias + SiLU.
// UPRE layout: [b, l, d] (d fastest). One thread per (b,l,d).
// ---------------------------------------------------------------------------
__global__ __launch_bounds__(256) void conv_silu(
    const float* __restrict__ UPRE, const float* __restrict__ cw,
    const float* __restrict__ cb, float* __restrict__ U) {
  int idx = blockIdx.x * 256 + threadIdx.x;   // B*L*DINNER total
  int d = idx & (DINNER - 1);
  int l = (idx >> 11) & (LSEQ - 1);
  int b = idx >> 21;
  float acc = cb[d];
#pragma unroll
  for (int k = 0; k < DCONV; ++k) {
    int ll = l + k - (DCONV - 1);
    if (ll >= 0)
      acc += UPRE[((size_t)(b * LSEQ + ll)) * DINNER + d] * cw[d * DCONV + k];
  }
  // SiLU
  U[idx] = acc / (1.f + expf(-acc));
}

// ---------------------------------------------------------------------------
// Selective scan. One thread per (b, d); 16-state recurrence in registers.
// Fuses: softplus(delta_pre + dt_bias), +u*D, *silu(res).
// BC[b,l,0:16]=Bx, [16:32]=Cx staged in LDS per 32-step chunk.
// ---------------------------------------------------------------------------
__global__ __launch_bounds__(256) void scan_kernel(
    const float* __restrict__ DELTA, const float* __restrict__ U,
    const float* __restrict__ BC, const float* __restrict__ RES,
    const float* __restrict__ dt_b, const float* __restrict__ A_log,
    const float* __restrict__ D_param, float* __restrict__ Y) {
  const int b = blockIdx.x >> 3;            // 8 blocks of 256 channels per batch
  const int d = ((blockIdx.x & 7) << 8) + threadIdx.x;
  __shared__ float sBC[32 * 32];            // 32 steps x (16 B + 16 C)

  float Av[DSTATE];
#pragma unroll
  for (int n = 0; n < DSTATE; ++n) Av[n] = -expf(A_log[d * DSTATE + n]);
  const float dtb = dt_b[d];
  const float Dp = D_param[d];
  float h[DSTATE];
#pragma unroll
  for (int n = 0; n < DSTATE; ++n) h[n] = 0.f;

  for (int l0 = 0; l0 < LSEQ; l0 += 32) {
    __syncthreads();
#pragma unroll
    for (int i = 0; i < 4; ++i) {
      int e = threadIdx.x + i * 256;
      sBC[e] = BC[((size_t)b * LSEQ + l0 + (e >> 5)) * 32 + (e & 31)];
    }
    __syncthreads();
    for (int lc = 0; lc < 32; ++lc) {
      size_t off = ((size_t)b * LSEQ + l0 + lc) * DINNER + d;
      float xp = DELTA[off] + dtb;
      float delta = (xp > 20.f) ? xp : log1pf(expf(xp));
      float uu = U[off];
      float du = delta * uu;
      float y = 0.f;
#pragma unroll
      for (int n = 0; n < DSTATE; ++n) {
        float dA = expf(delta * Av[n]);
        h[n] = dA * h[n] + du * sBC[lc * 32 + n];
        y += h[n] * sBC[lc * 32 + 16 + n];
      }
      y += uu * Dp;
      float r = RES[off];
      float sr = r / (1.f + expf(-r));
      Y[off] = y * sr;
    }
  }
}

// ---------------------------------------------------------------------------
extern "C" void kernel_launch(void* const* d_in, const int* in_sizes, int n_in,
                              void* d_out, int out_size, void* d_ws, size_t ws_size,
                              hipStream_t stream) {
  const float* x       = (const float*)d_in[0];  // (B,L,DMODEL)
  const float* w_in    = (const float*)d_in[1];  // (DMODEL, 2*DINNER)
  const float* conv_w  = (const float*)d_in[2];  // (DINNER,1,DCONV)
  const float* conv_b  = (const float*)d_in[3];  // (DINNER)
  const float* xproj_w = (const float*)d_in[4];  // (DINNER, 2*DSTATE)
  const float* dt_w    = (const float*)d_in[5];  // (DINNER, DINNER)
  const float* dt_b    = (const float*)d_in[6];  // (DINNER)
  const float* A_log   = (const float*)d_in[7];  // (DINNER, DSTATE)
  const float* D_par   = (const float*)d_in[8];  // (DINNER)
  const float* out_w   = (const float*)d_in[9];  // (DINNER, DMODEL)
  float* out = (float*)d_out;                    // (B,L,DMODEL)

  float* ws = (float*)d_ws;
  const size_t SZ = (size_t)NROWS * DINNER;      // 4,194,304
  float* UPRE  = ws;                 // [NROWS, DINNER] pre-conv u
  float* RES   = ws + SZ;            // [NROWS, DINNER]
  float* U     = ws + 2 * SZ;        // [NROWS, DINNER] post conv+silu
  float* DELTA = UPRE;               // alias: UPRE dead after conv
  float* BC    = ws + 3 * SZ;        // [NROWS, 32]
  float* Y     = BC + (size_t)NROWS * 32;  // [NROWS, DINNER]
  // total ws use: 4*SZ + NROWS*32 floats = ~64.3 MB

  dim3 blk(256);
  // 1+2) in_proj: X(2048x1024) @ W(1024x4096), split into u | res
  gemm_nn<<<dim3(DINNER / TILE, NROWS / TILE), blk, 0, stream>>>(
      x, DMODEL, w_in, 2 * DINNER, UPRE, DINNER, NROWS, DINNER, DMODEL);
  gemm_nn<<<dim3(DINNER / TILE, NROWS / TILE), blk, 0, stream>>>(
      x, DMODEL, w_in + DINNER, 2 * DINNER, RES, DINNER, NROWS, DINNER, DMODEL);
  // 3) depthwise conv + silu
  conv_silu<<<dim3((BATCH * LSEQ * DINNER) / 256), blk, 0, stream>>>(
      UPRE, conv_w, conv_b, U);
  // 4) x_proj: U(2048x2048) @ Wx(2048x32) -> BC
  gemm_nn<<<dim3(1, NROWS / TILE), blk, 0, stream>>>(
      U, DINNER, xproj_w, 2 * DSTATE, BC, 2 * DSTATE, NROWS, 2 * DSTATE, DINNER);
  // 5) dt_proj: U @ dt_w^T -> DELTA (pre-softplus)
  gemm_nt<<<dim3(DINNER / TILE, NROWS / TILE), blk, 0, stream>>>(
      U, DINNER, dt_w, DINNER, DELTA, DINNER, NROWS, DINNER, DINNER);
  // 6) selective scan + gating -> Y
  scan_kernel<<<dim3(BATCH * (DINNER / 256)), blk, 0, stream>>>(
      DELTA, U, BC, RES, dt_b, A_log, D_par, Y);
  // 7) out_proj: Y(2048x2048) @ Wo(2048x1024) -> out
  gemm_nn<<<dim3(DMODEL / TILE, NROWS / TILE), blk, 0, stream>>>(
      Y, DINNER, out_w, DMODEL, out, DMODEL, NROWS, DMODEL, DINNER);
}

// Round 2
// 1222.513 us; speedup vs baseline: 2.4534x; 2.4534x over previous
//
#include <hip/hip_runtime.h>
#include <math.h>

// Problem constants
#define BATCH   2
#define LSEQ    1024
#define DMODEL  1024
#define DSTATE  16
#define DCONV   4
#define DINNER  2048   // EXPAND * DMODEL
#define NROWS   (BATCH * LSEQ)   // 2048

// Chunked scan config
#define LCHUNK  32
#define NCHUNK  32     // LCHUNK * NCHUNK == LSEQ

// ---------------------------------------------------------------------------
// 128x128 fp32 GEMM (NN): C[m,n] = sum_k A[m*lda+k] * B[k*ldb+n]
// 256 threads, 8x8 microtile. Split-column epilogue: cols < N1 -> C1, else C2.
// Fragment columns are {t*4..t*4+3} u {64+t*4..} so b128 LDS reads are <=2-way
// bank conflicted (free on gfx950, m136).
// ---------------------------------------------------------------------------
#define GT   128
#define GKT  16
#define GLDP 132

__global__ __launch_bounds__(256) void gemm128_nn(
    const float* __restrict__ A, int lda,
    const float* __restrict__ Bm, int ldb,
    float* __restrict__ C1, int ld1,
    float* __restrict__ C2, int ld2, int N1,
    int K) {
  __shared__ float As[GKT * GLDP];
  __shared__ float Bs[GKT * GLDP];
  const int tid = threadIdx.x;
  const int tx = tid & 15;
  const int ty = tid >> 4;
  const int row0 = blockIdx.y * GT;
  const int col0 = blockIdx.x * GT;
  float acc[8][8] = {};
  for (int k0 = 0; k0 < K; k0 += GKT) {
#pragma unroll
    for (int i = 0; i < 8; ++i) {
      int e = tid + i * 256;
      int m = e >> 4, k = e & 15;
      As[k * GLDP + m] = A[(size_t)(row0 + m) * lda + k0 + k];
    }
#pragma unroll
    for (int i = 0; i < 8; ++i) {
      int e = tid + i * 256;
      int k = e >> 7, n = e & 127;
      Bs[k * GLDP + n] = Bm[(size_t)(k0 + k) * ldb + col0 + n];
    }
    __syncthreads();
#pragma unroll
    for (int kk = 0; kk < GKT; ++kk) {
      float a[8], b[8];
#pragma unroll
      for (int i = 0; i < 4; ++i) {
        a[i]     = As[kk * GLDP + ty * 4 + i];
        a[4 + i] = As[kk * GLDP + 64 + ty * 4 + i];
      }
#pragma unroll
      for (int j = 0; j < 4; ++j) {
        b[j]     = Bs[kk * GLDP + tx * 4 + j];
        b[4 + j] = Bs[kk * GLDP + 64 + tx * 4 + j];
      }
#pragma unroll
      for (int i = 0; i < 8; ++i)
#pragma unroll
        for (int j = 0; j < 8; ++j)
          acc[i][j] += a[i] * b[j];
    }
    __syncthreads();
  }
#pragma unroll
  for (int i = 0; i < 8; ++i) {
    int gm = row0 + ((i < 4) ? (ty * 4 + i) : (64 + ty * 4 + (i - 4)));
#pragma unroll
    for (int jh = 0; jh < 2; ++jh) {
      int gn = col0 + tx * 4 + jh * 64;
      float4 v = make_float4(acc[i][jh * 4 + 0], acc[i][jh * 4 + 1],
                             acc[i][jh * 4 + 2], acc[i][jh * 4 + 3]);
      if (gn < N1)
        *(float4*)&C1[(size_t)gm * ld1 + gn] = v;
      else
        *(float4*)&C2[(size_t)gm * ld2 + gn - N1] = v;
    }
  }
}

// ---------------------------------------------------------------------------
// 128x128 fp32 GEMM (NT): C[m,n] = sum_k A[m*lda+k] * Bt[n*ldb+k]
// ---------------------------------------------------------------------------
__global__ __launch_bounds__(256) void gemm128_nt(
    const float* __restrict__ A, int lda,
    const float* __restrict__ Bt, int ldb,
    float* __restrict__ C, int ldc, int K) {
  __shared__ float As[GKT * GLDP];
  __shared__ float Bs[GKT * GLDP];
  const int tid = threadIdx.x;
  const int tx = tid & 15;
  const int ty = tid >> 4;
  const int row0 = blockIdx.y * GT;
  const int col0 = blockIdx.x * GT;
  float acc[8][8] = {};
  for (int k0 = 0; k0 < K; k0 += GKT) {
#pragma unroll
    for (int i = 0; i < 8; ++i) {
      int e = tid + i * 256;
      int m = e >> 4, k = e & 15;
      As[k * GLDP + m] = A[(size_t)(row0 + m) * lda + k0 + k];
    }
#pragma unroll
    for (int i = 0; i < 8; ++i) {
      int e = tid + i * 256;
      int n = e >> 4, k = e & 15;
      Bs[k * GLDP + n] = Bt[(size_t)(col0 + n) * ldb + k0 + k];
    }
    __syncthreads();
#pragma unroll
    for (int kk = 0; kk < GKT; ++kk) {
      float a[8], b[8];
#pragma unroll
      for (int i = 0; i < 4; ++i) {
        a[i]     = As[kk * GLDP + ty * 4 + i];
        a[4 + i] = As[kk * GLDP + 64 + ty * 4 + i];
      }
#pragma unroll
      for (int j = 0; j < 4; ++j) {
        b[j]     = Bs[kk * GLDP + tx * 4 + j];
        b[4 + j] = Bs[kk * GLDP + 64 + tx * 4 + j];
      }
#pragma unroll
      for (int i = 0; i < 8; ++i)
#pragma unroll
        for (int j = 0; j < 8; ++j)
          acc[i][j] += a[i] * b[j];
    }
    __syncthreads();
  }
#pragma unroll
  for (int i = 0; i < 8; ++i) {
    int gm = row0 + ((i < 4) ? (ty * 4 + i) : (64 + ty * 4 + (i - 4)));
#pragma unroll
    for (int jh = 0; jh < 2; ++jh) {
      int gn = col0 + tx * 4 + jh * 64;
      float4 v = make_float4(acc[i][jh * 4 + 0], acc[i][jh * 4 + 1],
                             acc[i][jh * 4 + 2], acc[i][jh * 4 + 3]);
      *(float4*)&C[(size_t)gm * ldc + gn] = v;
    }
  }
}

// ---------------------------------------------------------------------------
// 64x64 fp32 GEMM with bounds (for the skinny x_proj, N=32).
// ---------------------------------------------------------------------------
#define TILE 64
#define KT   16
#define LDP  68

__global__ __launch_bounds__(256) void gemm64_nn(
    const float* __restrict__ A, int lda,
    const float* __restrict__ Bm, int ldb,
    float* __restrict__ C, int ldc,
    int M, int N, int K) {
  __shared__ float As[KT * LDP];
  __shared__ float Bs[KT * LDP];
  const int tid = threadIdx.x;
  const int tx = tid & 15;
  const int ty = tid >> 4;
  const int row0 = blockIdx.y * TILE;
  const int col0 = blockIdx.x * TILE;
  float acc[4][4] = {};
  for (int k0 = 0; k0 < K; k0 += KT) {
#pragma unroll
    for (int i = 0; i < 4; ++i) {
      int e = tid + i * 256;
      int m = e >> 4, k = e & 15;
      int gm = row0 + m, gk = k0 + k;
      As[k * LDP + m] = (gm < M && gk < K) ? A[(size_t)gm * lda + gk] : 0.f;
    }
#pragma unroll
    for (int i = 0; i < 4; ++i) {
      int e = tid + i * 256;
      int k = e >> 6, n = e & 63;
      int gk = k0 + k, gn = col0 + n;
      Bs[k * LDP + n] = (gk < K && gn < N) ? Bm[(size_t)gk * ldb + gn] : 0.f;
    }
    __syncthreads();
#pragma unroll
    for (int kk = 0; kk < KT; ++kk) {
      float a[4], b[4];
#pragma unroll
      for (int i = 0; i < 4; ++i) a[i] = As[kk * LDP + ty * 4 + i];
#pragma unroll
      for (int j = 0; j < 4; ++j) b[j] = Bs[kk * LDP + tx * 4 + j];
#pragma unroll
      for (int i = 0; i < 4; ++i)
#pragma unroll
        for (int j = 0; j < 4; ++j)
          acc[i][j] += a[i] * b[j];
    }
    __syncthreads();
  }
#pragma unroll
  for (int i = 0; i < 4; ++i) {
    int gm = row0 + ty * 4 + i;
    if (gm >= M) continue;
#pragma unroll
    for (int j = 0; j < 4; ++j) {
      int gn = col0 + tx * 4 + j;
      if (gn < N) C[(size_t)gm * ldc + gn] = acc[i][j];
    }
  }
}

// ---------------------------------------------------------------------------
// Depthwise causal conv (width 4) + bias + SiLU. Layout [b,l,d], d fastest.
// ---------------------------------------------------------------------------
__global__ __launch_bounds__(256) void conv_silu(
    const float* __restrict__ UPRE, const float* __restrict__ cw,
    const float* __restrict__ cb, float* __restrict__ U) {
  int idx = blockIdx.x * 256 + threadIdx.x;
  int d = idx & (DINNER - 1);
  int l = (idx >> 11) & (LSEQ - 1);
  int b = idx >> 21;
  float acc = cb[d];
#pragma unroll
  for (int k = 0; k < DCONV; ++k) {
    int ll = l + k - (DCONV - 1);
    if (ll >= 0)
      acc += UPRE[((size_t)(b * LSEQ + ll)) * DINNER + d] * cw[d * DCONV + k];
  }
  U[idx] = acc / (1.f + __expf(-acc));
}

// ---------------------------------------------------------------------------
// Scan pass 1: per (b, chunk, d) compute chunk decay product P[n] and local
// state h_loc[n] (h0 = 0). grid = B * NCHUNK * (DINNER/256) = 512 blocks.
// PBUF/HBUF layout: [b][c][n][d] (d fastest, coalesced).
// ---------------------------------------------------------------------------
__global__ __launch_bounds__(256) void scan_pass1(
    const float* __restrict__ DELTA, const float* __restrict__ U,
    const float* __restrict__ BC, const float* __restrict__ dt_b,
    const float* __restrict__ A_log,
    float* __restrict__ PBUF, float* __restrict__ HBUF) {
  const int bx = blockIdx.x;
  const int b = bx >> 8;               // NCHUNK*8 = 256 blocks per batch
  const int c = (bx >> 3) & (NCHUNK - 1);
  const int d = ((bx & 7) << 8) + threadIdx.x;
  const int l0 = c * LCHUNK;
  __shared__ float sB[LCHUNK * DSTATE];
#pragma unroll
  for (int i = 0; i < 2; ++i) {
    int e = threadIdx.x + i * 256;
    sB[e] = BC[((size_t)(b * LSEQ + l0 + (e >> 4))) * 32 + (e & 15)];
  }
  float Av[DSTATE];
#pragma unroll
  for (int n = 0; n < DSTATE; ++n) Av[n] = -__expf(A_log[d * DSTATE + n]);
  const float dtb = dt_b[d];
  float h[DSTATE], P[DSTATE];
#pragma unroll
  for (int n = 0; n < DSTATE; ++n) { h[n] = 0.f; P[n] = 1.f; }
  __syncthreads();
  for (int lc = 0; lc < LCHUNK; ++lc) {
    size_t off = ((size_t)(b * LSEQ + l0 + lc)) * DINNER + d;
    float xp = DELTA[off] + dtb;
    float delta = (xp > 20.f) ? xp : __logf(1.f + __expf(xp));
    float du = delta * U[off];
#pragma unroll
    for (int n = 0; n < DSTATE; ++n) {
      float dA = __expf(delta * Av[n]);
      P[n] *= dA;
      h[n] = dA * h[n] + du * sB[lc * DSTATE + n];
    }
  }
  size_t base = ((size_t)(b * NCHUNK + c)) * DSTATE * DINNER + d;
#pragma unroll
  for (int n = 0; n < DSTATE; ++n) {
    PBUF[base + (size_t)n * DINNER] = P[n];
    HBUF[base + (size_t)n * DINNER] = h[n];
  }
}

// ---------------------------------------------------------------------------
// Scan pass 2 (combine): sequential prefix across chunks, one thread per
// (b, n, d) — states independent. Overwrites HBUF[c] with the INCOMING state
// for chunk c (read h_loc first, then store). grid = B*DSTATE*8 = 256 blocks.
// ---------------------------------------------------------------------------
__global__ __launch_bounds__(256) void scan_combine(
    const float* __restrict__ PBUF, float* __restrict__ HBUF) {
  const int bx = blockIdx.x;
  const int b = bx >> 7;               // DSTATE*8 = 128 blocks per batch
  const int n = (bx >> 3) & (DSTATE - 1);
  const int d = ((bx & 7) << 8) + threadIdx.x;
  float h = 0.f;
  for (int c = 0; c < NCHUNK; ++c) {
    size_t idx = (((size_t)(b * NCHUNK + c)) * DSTATE + n) * DINNER + d;
    float p = PBUF[idx];
    float hl = HBUF[idx];
    HBUF[idx] = h;
    h = p * h + hl;
  }
}

// ---------------------------------------------------------------------------
// Scan pass 3: rescan each chunk from its true incoming state, emit
// y = C.h + u*D, gated by silu(res). RESY is read-then-written in place
// (each element owned by exactly one thread) — NOT restrict-qualified.
// ---------------------------------------------------------------------------
__global__ __launch_bounds__(256) void scan_pass2(
    const float* __restrict__ DELTA, const float* __restrict__ U,
    const float* __restrict__ BC, const float* __restrict__ HBUF,
    const float* __restrict__ dt_b, const float* __restrict__ A_log,
    const float* __restrict__ D_param, float* RESY) {
  const int bx = blockIdx.x;
  const int b = bx >> 8;
  const int c = (bx >> 3) & (NCHUNK - 1);
  const int d = ((bx & 7) << 8) + threadIdx.x;
  const int l0 = c * LCHUNK;
  __shared__ float sBC[LCHUNK * 32];
#pragma unroll
  for (int i = 0; i < 4; ++i) {
    int e = threadIdx.x + i * 256;
    sBC[e] = BC[((size_t)(b * LSEQ + l0 + (e >> 5))) * 32 + (e & 31)];
  }
  float Av[DSTATE];
#pragma unroll
  for (int n = 0; n < DSTATE; ++n) Av[n] = -__expf(A_log[d * DSTATE + n]);
  const float dtb = dt_b[d];
  const float Dp = D_param[d];
  float h[DSTATE];
  size_t base = ((size_t)(b * NCHUNK + c)) * DSTATE * DINNER + d;
#pragma unroll
  for (int n = 0; n < DSTATE; ++n) h[n] = HBUF[base + (size_t)n * DINNER];
  __syncthreads();
  for (int lc = 0; lc < LCHUNK; ++lc) {
    size_t off = ((size_t)(b * LSEQ + l0 + lc)) * DINNER + d;
    float xp = DELTA[off] + dtb;
    float delta = (xp > 20.f) ? xp : __logf(1.f + __expf(xp));
    float uu = U[off];
    float du = delta * uu;
    float y = 0.f;
#pragma unroll
    for (int n = 0; n < DSTATE; ++n) {
      float dA = __expf(delta * Av[n]);
      h[n] = dA * h[n] + du * sBC[lc * 32 + n];
      y += h[n] * sBC[lc * 32 + 16 + n];
    }
    y += uu * Dp;
    float r = RESY[off];
    RESY[off] = y * (r / (1.f + __expf(-r)));
  }
}

// ---------------------------------------------------------------------------
extern "C" void kernel_launch(void* const* d_in, const int* in_sizes, int n_in,
                              void* d_out, int out_size, void* d_ws, size_t ws_size,
                              hipStream_t stream) {
  const float* x       = (const float*)d_in[0];
  const float* w_in    = (const float*)d_in[1];
  const float* conv_w  = (const float*)d_in[2];
  const float* conv_b  = (const float*)d_in[3];
  const float* xproj_w = (const float*)d_in[4];
  const float* dt_w    = (const float*)d_in[5];
  const float* dt_b    = (const float*)d_in[6];
  const float* A_log   = (const float*)d_in[7];
  const float* D_par   = (const float*)d_in[8];
  const float* out_w   = (const float*)d_in[9];
  float* out = (float*)d_out;

  float* ws = (float*)d_ws;
  const size_t SZ = (size_t)NROWS * DINNER;
  float* UPRE  = ws;                  // [NROWS, DINNER]; aliased by DELTA
  float* RES   = ws + SZ;             // [NROWS, DINNER]; aliased by Y (in-place gate)
  float* U     = ws + 2 * SZ;         // [NROWS, DINNER]
  float* DELTA = UPRE;
  float* BC    = ws + 3 * SZ;         // [NROWS, 32]
  float* PBUF  = BC + (size_t)NROWS * 32;
  float* HBUF  = PBUF + (size_t)BATCH * NCHUNK * DSTATE * DINNER;
  // total: 3*SZ + 65536 + 2*2097152 floats = 67.4 MB (same as round-1 safe usage)

  dim3 blk(256);
  // in_proj: X(2048x1024) @ W(1024x4096) -> [UPRE | RES] in one launch
  gemm128_nn<<<dim3((2 * DINNER) / GT, NROWS / GT), blk, 0, stream>>>(
      x, DMODEL, w_in, 2 * DINNER, UPRE, DINNER, RES, DINNER, DINNER, DMODEL);
  // depthwise conv + silu
  conv_silu<<<dim3((BATCH * LSEQ * DINNER) / 256), blk, 0, stream>>>(
      UPRE, conv_w, conv_b, U);
  // x_proj: U @ Wx(2048x32) -> BC
  gemm64_nn<<<dim3(1, NROWS / TILE), blk, 0, stream>>>(
      U, DINNER, xproj_w, 2 * DSTATE, BC, 2 * DSTATE, NROWS, 2 * DSTATE, DINNER);
  // dt_proj: U @ dt_w^T -> DELTA
  gemm128_nt<<<dim3(DINNER / GT, NROWS / GT), blk, 0, stream>>>(
      U, DINNER, dt_w, DINNER, DELTA, DINNER, DINNER);
  // chunked selective scan
  scan_pass1<<<dim3(BATCH * NCHUNK * (DINNER / 256)), blk, 0, stream>>>(
      DELTA, U, BC, dt_b, A_log, PBUF, HBUF);
  scan_combine<<<dim3(BATCH * DSTATE * (DINNER / 256)), blk, 0, stream>>>(
      PBUF, HBUF);
  scan_pass2<<<dim3(BATCH * NCHUNK * (DINNER / 256)), blk, 0, stream>>>(
      DELTA, U, BC, HBUF, dt_b, A_log, D_par, RES);
  // out_proj: Y(=RES) @ Wo(2048x1024) -> out
  gemm128_nn<<<dim3(DMODEL / GT, NROWS / GT), blk, 0, stream>>>(
      RES, DINNER, out_w, DMODEL, out, DMODEL, out, DMODEL, DMODEL, DINNER);
}

// Round 3
// 391.713 us; speedup vs baseline: 7.6570x; 3.1209x over previous
//
#include <hip/hip_runtime.h>
#include <math.h>

// Problem constants
#define BATCH   2
#define LSEQ    1024
#define DMODEL  1024
#define DSTATE  16
#define DCONV   4
#define DINNER  2048
#define NROWS   (BATCH * LSEQ)   // 2048

#define LCHUNK  32
#define NCHUNK  32

typedef short  bf16x8 __attribute__((ext_vector_type(8)));
typedef float  f32x4  __attribute__((ext_vector_type(4)));

__device__ __forceinline__ unsigned short f2bf(float f) {
  unsigned int u = __builtin_bit_cast(unsigned int, f);
  u = (u + 0x7fffu + ((u >> 16) & 1u)) >> 16;   // RNE
  return (unsigned short)u;
}
__device__ __forceinline__ float bf2f(unsigned short h) {
  return __builtin_bit_cast(float, (unsigned int)h << 16);
}

// ---------------------------------------------------------------------------
// fp32 -> bf16 elementwise (4 elems/thread)
// ---------------------------------------------------------------------------
__global__ __launch_bounds__(256) void cvt_ew(
    const float* __restrict__ s, unsigned short* __restrict__ d) {
  int i = blockIdx.x * 256 + threadIdx.x;
  float4 v = ((const float4*)s)[i];
  ushort4 o;
  o.x = f2bf(v.x); o.y = f2bf(v.y); o.z = f2bf(v.z); o.w = f2bf(v.w);
  ((ushort4*)d)[i] = o;
}

// ---------------------------------------------------------------------------
// fp32 [R][C] -> bf16 [C][R] transpose-convert. 32x32 LDS tile.
// grid: (C/32, R/32)
// ---------------------------------------------------------------------------
__global__ __launch_bounds__(256) void cvt_tr(
    const float* __restrict__ s, unsigned short* __restrict__ d, int R, int C) {
  __shared__ float T[32][33];
  const int c0 = blockIdx.x * 32, r0 = blockIdx.y * 32;
  const int tid = threadIdx.x;
#pragma unroll
  for (int i = 0; i < 4; ++i) {
    int e = tid + i * 256;
    int r = e >> 5, c = e & 31;
    T[r][c] = s[(size_t)(r0 + r) * C + c0 + c];
  }
  __syncthreads();
#pragma unroll
  for (int i = 0; i < 4; ++i) {
    int e = tid + i * 256;
    int c = e >> 5, r = e & 31;
    d[(size_t)(c0 + c) * R + r0 + r] = f2bf(T[r][c]);
  }
}

// ---------------------------------------------------------------------------
// bf16 MFMA GEMM (NT): C[m,n] = sum_k A[m][k] * Bt[n][k], fp32 out.
// A: M x K bf16 row-major; Bt: N x K bf16 row-major.
// 128x128 tile, BK=32, 256 threads = 4 waves, each wave 64x64 (4x4 MFMAs of
// 16x16x32). LDS layout: slot s (16B = 8 bf16): kc=s>>7 (k-chunk of 8),
// r=s&127 (row) -> fragment ds_read_b128 is contiguous across lanes 0..15
// (<=2-way bank aliasing, free). Staged with global_load_lds width=16.
// Split-column epilogue: col < N1 -> C1 else C2 (dims all multiples of 128).
// ---------------------------------------------------------------------------
__global__ __launch_bounds__(256) void mfma_gemm_nt(
    const unsigned short* __restrict__ A, int lda,
    const unsigned short* __restrict__ Bt, int ldb,
    float* __restrict__ C1, int ld1,
    float* __restrict__ C2, int ld2, int N1, int K) {
  __shared__ unsigned short As[4 * 128 * 8];  // 8 KB
  __shared__ unsigned short Bs[4 * 128 * 8];  // 8 KB
  const int tid  = threadIdx.x;
  const int wave = tid >> 6;
  const int lane = tid & 63;
  const int row0 = blockIdx.y * 128;
  const int col0 = blockIdx.x * 128;
  const int wm0 = (wave >> 1) * 64;
  const int wn0 = (wave & 1) * 64;
  f32x4 acc[4][4];
#pragma unroll
  for (int i = 0; i < 4; ++i)
#pragma unroll
    for (int j = 0; j < 4; ++j) acc[i][j] = (f32x4){0.f, 0.f, 0.f, 0.f};

  const int lkc = lane >> 4, li = lane & 15;
  for (int k0 = 0; k0 < K; k0 += 32) {
#pragma unroll
    for (int it = 0; it < 2; ++it) {
      int s = it * 256 + tid;        // 0..511
      int kc = s >> 7, r = s & 127;
      __builtin_amdgcn_global_load_lds(
          (const __attribute__((address_space(1))) void*)(A + (size_t)(row0 + r) * lda + k0 + kc * 8),
          (__attribute__((address_space(3))) void*)(&As[s * 8]), 16, 0, 0);
      __builtin_amdgcn_global_load_lds(
          (const __attribute__((address_space(1))) void*)(Bt + (size_t)(col0 + r) * ldb + k0 + kc * 8),
          (__attribute__((address_space(3))) void*)(&Bs[s * 8]), 16, 0, 0);
    }
    __syncthreads();
    bf16x8 af[4], bfr[4];
#pragma unroll
    for (int mt = 0; mt < 4; ++mt)
      af[mt] = *(const bf16x8*)&As[(lkc * 128 + wm0 + mt * 16 + li) * 8];
#pragma unroll
    for (int nt = 0; nt < 4; ++nt)
      bfr[nt] = *(const bf16x8*)&Bs[(lkc * 128 + wn0 + nt * 16 + li) * 8];
#pragma unroll
    for (int mt = 0; mt < 4; ++mt)
#pragma unroll
      for (int nt = 0; nt < 4; ++nt)
        acc[mt][nt] = __builtin_amdgcn_mfma_f32_16x16x32_bf16(
            af[mt], bfr[nt], acc[mt][nt], 0, 0, 0);
    __syncthreads();
  }
  // Epilogue: C/D layout col=lane&15, row=(lane>>4)*4+reg (m89-verified)
  const int lq = lane >> 4;
#pragma unroll
  for (int mt = 0; mt < 4; ++mt) {
    int gm0 = row0 + wm0 + mt * 16 + lq * 4;
#pragma unroll
    for (int nt = 0; nt < 4; ++nt) {
      int gn = col0 + wn0 + nt * 16 + li;
      float* Cp; int ld, cn;
      if (gn < N1) { Cp = C1; ld = ld1; cn = gn; }
      else         { Cp = C2; ld = ld2; cn = gn - N1; }
#pragma unroll
      for (int r = 0; r < 4; ++r)
        Cp[(size_t)(gm0 + r) * ld + cn] = acc[mt][nt][r];
    }
  }
}

// ---------------------------------------------------------------------------
// Depthwise causal conv (width 4) + bias + SiLU -> bf16 U.
// ---------------------------------------------------------------------------
__global__ __launch_bounds__(256) void conv_silu(
    const float* __restrict__ UPRE, const float* __restrict__ cw,
    const float* __restrict__ cb, unsigned short* __restrict__ UB) {
  int idx = blockIdx.x * 256 + threadIdx.x;
  int d = idx & (DINNER - 1);
  int l = (idx >> 11) & (LSEQ - 1);
  int b = idx >> 21;
  float acc = cb[d];
#pragma unroll
  for (int k = 0; k < DCONV; ++k) {
    int ll = l + k - (DCONV - 1);
    if (ll >= 0)
      acc += UPRE[((size_t)(b * LSEQ + ll)) * DINNER + d] * cw[d * DCONV + k];
  }
  UB[idx] = f2bf(acc / (1.f + __expf(-acc)));
}

// ---------------------------------------------------------------------------
// x_proj split-K: partial C[64 rows][32 cols] over K-slice of 256.
// grid (8 kslices, 32 rowtiles). XPART[ks][row][col] fp32.
// ---------------------------------------------------------------------------
__global__ __launch_bounds__(256) void xproj_partial(
    const unsigned short* __restrict__ UB, const float* __restrict__ W,
    float* __restrict__ XPART) {
  const int ks = blockIdx.x;
  const int row0 = blockIdx.y * 64;
  const int kbase = ks * 256;
  __shared__ float Av[16][68];   // [k][row]
  __shared__ float Bv[16][32];   // [k][col]
  const int tid = threadIdx.x;
  const int col = tid & 31, rg = tid >> 5;   // 8 row-groups x 8 rows
  float acc[8] = {};
  for (int kk = 0; kk < 256; kk += 16) {
#pragma unroll
    for (int i = 0; i < 4; ++i) {
      int e = tid + i * 256;
      int r = e >> 4, k = e & 15;
      Av[k][r] = bf2f(UB[(size_t)(row0 + r) * DINNER + kbase + kk + k]);
    }
#pragma unroll
    for (int i = 0; i < 2; ++i) {
      int e = tid + i * 256;
      int k = e >> 5, c = e & 31;
      Bv[k][c] = W[(size_t)(kbase + kk + k) * 32 + c];
    }
    __syncthreads();
#pragma unroll
    for (int k = 0; k < 16; ++k) {
      float b = Bv[k][col];
#pragma unroll
      for (int r = 0; r < 8; ++r) acc[r] += Av[k][rg * 8 + r] * b;
    }
    __syncthreads();
  }
#pragma unroll
  for (int r = 0; r < 8; ++r)
    XPART[(size_t)ks * NROWS * 32 + (size_t)(row0 + rg * 8 + r) * 32 + col] = acc[r];
}

__global__ __launch_bounds__(256) void xproj_reduce(
    const float* __restrict__ XPART, float* __restrict__ BC) {
  int i = blockIdx.x * 256 + threadIdx.x;   // 65536
  float s = 0.f;
#pragma unroll
  for (int ks = 0; ks < 8; ++ks) s += XPART[(size_t)ks * NROWS * 32 + i];
  BC[i] = s;
}

// ---------------------------------------------------------------------------
// Scan pass 1: per-chunk decay product P and local state h (h0=0).
// ---------------------------------------------------------------------------
__global__ __launch_bounds__(256) void scan_pass1(
    const float* __restrict__ DELTA, const unsigned short* __restrict__ UB,
    const float* __restrict__ BC, const float* __restrict__ dt_b,
    const float* __restrict__ A_log,
    float* __restrict__ PBUF, float* __restrict__ HBUF) {
  const int bx = blockIdx.x;
  const int b = bx >> 8;
  const int c = (bx >> 3) & (NCHUNK - 1);
  const int d = ((bx & 7) << 8) + threadIdx.x;
  const int l0 = c * LCHUNK;
  __shared__ float sB[LCHUNK * DSTATE];
#pragma unroll
  for (int i = 0; i < 2; ++i) {
    int e = threadIdx.x + i * 256;
    sB[e] = BC[((size_t)(b * LSEQ + l0 + (e >> 4))) * 32 + (e & 15)];
  }
  float Avv[DSTATE];
#pragma unroll
  for (int n = 0; n < DSTATE; ++n) Avv[n] = -__expf(A_log[d * DSTATE + n]);
  const float dtb = dt_b[d];
  float h[DSTATE], P[DSTATE];
#pragma unroll
  for (int n = 0; n < DSTATE; ++n) { h[n] = 0.f; P[n] = 1.f; }
  __syncthreads();
  for (int lc = 0; lc < LCHUNK; ++lc) {
    size_t off = ((size_t)(b * LSEQ + l0 + lc)) * DINNER + d;
    float xp = DELTA[off] + dtb;
    float delta = (xp > 20.f) ? xp : __logf(1.f + __expf(xp));
    float du = delta * bf2f(UB[off]);
#pragma unroll
    for (int n = 0; n < DSTATE; ++n) {
      float dA = __expf(delta * Avv[n]);
      P[n] *= dA;
      h[n] = dA * h[n] + du * sB[lc * DSTATE + n];
    }
  }
  size_t base = ((size_t)(b * NCHUNK + c)) * DSTATE * DINNER + d;
#pragma unroll
  for (int n = 0; n < DSTATE; ++n) {
    PBUF[base + (size_t)n * DINNER] = P[n];
    HBUF[base + (size_t)n * DINNER] = h[n];
  }
}

// ---------------------------------------------------------------------------
// Scan combine: sequential prefix across 32 chunks per (b,n,d).
// ---------------------------------------------------------------------------
__global__ __launch_bounds__(256) void scan_combine(
    const float* __restrict__ PBUF, float* __restrict__ HBUF) {
  const int bx = blockIdx.x;
  const int b = bx >> 7;
  const int n = (bx >> 3) & (DSTATE - 1);
  const int d = ((bx & 7) << 8) + threadIdx.x;
  float h = 0.f;
  for (int c = 0; c < NCHUNK; ++c) {
    size_t idx = (((size_t)(b * NCHUNK + c)) * DSTATE + n) * DINNER + d;
    float p = PBUF[idx];
    float hl = HBUF[idx];
    HBUF[idx] = h;
    h = p * h + hl;
  }
}

// ---------------------------------------------------------------------------
// Scan pass 2: rescan from true incoming state; y = C.h + u*D, gated by
// silu(res); emit bf16 Y for the out_proj MFMA GEMM.
// ---------------------------------------------------------------------------
__global__ __launch_bounds__(256) void scan_pass2(
    const float* __restrict__ DELTA, const unsigned short* __restrict__ UB,
    const float* __restrict__ BC, const float* __restrict__ HBUF,
    const float* __restrict__ dt_b, const float* __restrict__ A_log,
    const float* __restrict__ D_param, const float* __restrict__ RES,
    unsigned short* __restrict__ YB) {
  const int bx = blockIdx.x;
  const int b = bx >> 8;
  const int c = (bx >> 3) & (NCHUNK - 1);
  const int d = ((bx & 7) << 8) + threadIdx.x;
  const int l0 = c * LCHUNK;
  __shared__ float sBC[LCHUNK * 32];
#pragma unroll
  for (int i = 0; i < 4; ++i) {
    int e = threadIdx.x + i * 256;
    sBC[e] = BC[((size_t)(b * LSEQ + l0 + (e >> 5))) * 32 + (e & 31)];
  }
  float Avv[DSTATE];
#pragma unroll
  for (int n = 0; n < DSTATE; ++n) Avv[n] = -__expf(A_log[d * DSTATE + n]);
  const float dtb = dt_b[d];
  const float Dp = D_param[d];
  float h[DSTATE];
  size_t base = ((size_t)(b * NCHUNK + c)) * DSTATE * DINNER + d;
#pragma unroll
  for (int n = 0; n < DSTATE; ++n) h[n] = HBUF[base + (size_t)n * DINNER];
  __syncthreads();
  for (int lc = 0; lc < LCHUNK; ++lc) {
    size_t off = ((size_t)(b * LSEQ + l0 + lc)) * DINNER + d;
    float xp = DELTA[off] + dtb;
    float delta = (xp > 20.f) ? xp : __logf(1.f + __expf(xp));
    float uu = bf2f(UB[off]);
    float du = delta * uu;
    float y = 0.f;
#pragma unroll
    for (int n = 0; n < DSTATE; ++n) {
      float dA = __expf(delta * Avv[n]);
      h[n] = dA * h[n] + du * sBC[lc * 32 + n];
      y += h[n] * sBC[lc * 32 + 16 + n];
    }
    y += uu * Dp;
    float r = RES[off];
    YB[off] = f2bf(y * (r / (1.f + __expf(-r))));
  }
}

// ---------------------------------------------------------------------------
extern "C" void kernel_launch(void* const* d_in, const int* in_sizes, int n_in,
                              void* d_out, int out_size, void* d_ws, size_t ws_size,
                              hipStream_t stream) {
  const float* x       = (const float*)d_in[0];
  const float* w_in    = (const float*)d_in[1];
  const float* conv_w  = (const float*)d_in[2];
  const float* conv_b  = (const float*)d_in[3];
  const float* xproj_w = (const float*)d_in[4];
  const float* dt_w    = (const float*)d_in[5];
  const float* dt_b    = (const float*)d_in[6];
  const float* A_log   = (const float*)d_in[7];
  const float* D_par   = (const float*)d_in[8];
  const float* out_w   = (const float*)d_in[9];
  float* out = (float*)d_out;

  char* ws = (char*)d_ws;
  const size_t MB = 1024 * 1024;
  // fp32 buffers
  float* UPRE  = (float*)(ws + 0 * MB);          // 16 MB; aliased by DELTA
  float* RES   = (float*)(ws + 16 * MB);         // 16 MB
  float* DELTA = UPRE;
  // bf16 buffers
  unsigned short* UB   = (unsigned short*)(ws + 32 * MB);  // 8 MB
  unsigned short* YB   = (unsigned short*)(ws + 40 * MB);  // 8 MB
  unsigned short* XB   = (unsigned short*)(ws + 48 * MB);  // 4 MB (dead after in_proj)
  unsigned short* WINB = (unsigned short*)(ws + 52 * MB);  // 8 MB (dead after in_proj)
  unsigned short* DTWB = (unsigned short*)(ws + 60 * MB);  // 8 MB (dead after dt_proj)
  unsigned short* OWB  = (unsigned short*)(ws + 68 * MB);  // 4 MB (live to end)
  // overlays (first written after their underlying buffers die)
  float* PBUF  = (float*)(ws + 48 * MB);         // 8 MB over XB+WINB[lo]
  float* BCb   = (float*)(ws + 56 * MB);         // 256 KB over WINB[hi]
  float* XPART = (float*)(ws + 56 * MB + 512 * 1024);  // 2 MB over WINB[hi]
  float* HBUF  = (float*)(ws + 60 * MB);         // 8 MB over DTWB
  // footprint: 72 MB

  dim3 blk(256);
  // convert inputs to bf16 (weights transposed to [N][K])
  cvt_ew<<<dim3(NROWS * DMODEL / 1024), blk, 0, stream>>>(x, XB);
  cvt_tr<<<dim3(2 * DINNER / 32, DMODEL / 32), blk, 0, stream>>>(w_in, WINB, DMODEL, 2 * DINNER);
  cvt_ew<<<dim3(DINNER * DINNER / 1024), blk, 0, stream>>>(dt_w, DTWB);
  cvt_tr<<<dim3(DMODEL / 32, DINNER / 32), blk, 0, stream>>>(out_w, OWB, DINNER, DMODEL);
  // in_proj: XB(2048x1024) x WINB(4096x1024)^T -> [UPRE | RES] fp32
  mfma_gemm_nt<<<dim3(2 * DINNER / 128, NROWS / 128), blk, 0, stream>>>(
      XB, DMODEL, WINB, DMODEL, UPRE, DINNER, RES, DINNER, DINNER, DMODEL);
  // conv + silu -> UB bf16
  conv_silu<<<dim3(NROWS * DINNER / 256), blk, 0, stream>>>(UPRE, conv_w, conv_b, UB);
  // x_proj split-K -> BC
  xproj_partial<<<dim3(8, NROWS / 64), blk, 0, stream>>>(UB, xproj_w, XPART);
  xproj_reduce<<<dim3(NROWS * 32 / 256), blk, 0, stream>>>(XPART, BCb);
  // dt_proj: UB(2048x2048) x DTWB(2048x2048)^T -> DELTA fp32
  mfma_gemm_nt<<<dim3(DINNER / 128, NROWS / 128), blk, 0, stream>>>(
      UB, DINNER, DTWB, DINNER, DELTA, DINNER, DELTA, DINNER, DINNER, DINNER);
  // chunked selective scan
  scan_pass1<<<dim3(BATCH * NCHUNK * (DINNER / 256)), blk, 0, stream>>>(
      DELTA, UB, BCb, dt_b, A_log, PBUF, HBUF);
  scan_combine<<<dim3(BATCH * DSTATE * (DINNER / 256)), blk, 0, stream>>>(PBUF, HBUF);
  scan_pass2<<<dim3(BATCH * NCHUNK * (DINNER / 256)), blk, 0, stream>>>(
      DELTA, UB, BCb, HBUF, dt_b, A_log, D_par, RES, YB);
  // out_proj: YB(2048x2048) x OWB(1024x2048)^T -> out fp32
  mfma_gemm_nt<<<dim3(DMODEL / 128, NROWS / 128), blk, 0, stream>>>(
      YB, DINNER, OWB, DINNER, out, DMODEL, out, DMODEL, DMODEL, DINNER);
}

// Round 4
// 358.695 us; speedup vs baseline: 8.3618x; 1.0921x over previous
//
#include <hip/hip_runtime.h>
#include <math.h>

// Problem constants
#define BATCH   2
#define LSEQ    1024
#define DMODEL  1024
#define DSTATE  16
#define DCONV   4
#define DINNER  2048
#define NROWS   (BATCH * LSEQ)   // 2048

#define LCHUNK  32
#define NCHUNK  32

typedef short  bf16x8 __attribute__((ext_vector_type(8)));
typedef float  f32x4  __attribute__((ext_vector_type(4)));

__device__ __forceinline__ unsigned short f2bf(float f) {
  unsigned int u = __builtin_bit_cast(unsigned int, f);
  u = (u + 0x7fffu + ((u >> 16) & 1u)) >> 16;   // RNE
  return (unsigned short)u;
}
__device__ __forceinline__ float bf2f(unsigned short h) {
  return __builtin_bit_cast(float, (unsigned int)h << 16);
}

// ---------------------------------------------------------------------------
// fp32 -> bf16 elementwise (4 elems/thread)
// ---------------------------------------------------------------------------
__global__ __launch_bounds__(256) void cvt_ew(
    const float* __restrict__ s, unsigned short* __restrict__ d) {
  int i = blockIdx.x * 256 + threadIdx.x;
  float4 v = ((const float4*)s)[i];
  ushort4 o;
  o.x = f2bf(v.x); o.y = f2bf(v.y); o.z = f2bf(v.z); o.w = f2bf(v.w);
  ((ushort4*)d)[i] = o;
}

// ---------------------------------------------------------------------------
// fp32 [R][C] -> bf16 [C][R] transpose-convert. 32x32 LDS tile.
// ---------------------------------------------------------------------------
__global__ __launch_bounds__(256) void cvt_tr(
    const float* __restrict__ s, unsigned short* __restrict__ d, int R, int C) {
  __shared__ float T[32][33];
  const int c0 = blockIdx.x * 32, r0 = blockIdx.y * 32;
  const int tid = threadIdx.x;
#pragma unroll
  for (int i = 0; i < 4; ++i) {
    int e = tid + i * 256;
    int r = e >> 5, c = e & 31;
    T[r][c] = s[(size_t)(r0 + r) * C + c0 + c];
  }
  __syncthreads();
#pragma unroll
  for (int i = 0; i < 4; ++i) {
    int e = tid + i * 256;
    int c = e >> 5, r = e & 31;
    d[(size_t)(c0 + c) * R + r0 + r] = f2bf(T[r][c]);
  }
}

// ---------------------------------------------------------------------------
// bf16 MFMA GEMM (NT), occupancy-shaped for small grids:
// 128(M) x 64(N) block, 4 waves, each wave 64x32 = 4x2 MFMAs of 16x16x32.
// BK=32. LDS 12 KB -> with 512+ blocks we get >=2 blocks/CU, >=2 waves/SIMD.
// Split-K via gridDim.z: slice z covers K-range [z*KS, (z+1)*KS), output
// shifted by z*zstride (fp32 partials; S=1 -> zstride=0).
// Split-column epilogue: col < N1 -> C1 else C2 (BN=64 never straddles).
// ---------------------------------------------------------------------------
__global__ __launch_bounds__(256) void mfma_gemm_nt(
    const unsigned short* __restrict__ A, int lda,
    const unsigned short* __restrict__ Bt, int ldb,
    float* __restrict__ C1, int ld1,
    float* __restrict__ C2, int ld2, int N1,
    int KS, size_t zstride) {
  __shared__ unsigned short As[4 * 128 * 8];  // 8 KB  [kc][row][8]
  __shared__ unsigned short Bs[4 * 64 * 8];   // 4 KB  [kc][row][8]
  const int tid  = threadIdx.x;
  const int wave = tid >> 6;
  const int lane = tid & 63;
  const int row0 = blockIdx.y * 128;
  const int col0 = blockIdx.x * 64;
  const int wm0 = (wave >> 1) * 64;
  const int wn0 = (wave & 1) * 32;
  const int kb = blockIdx.z * KS;
  f32x4 acc[4][2];
#pragma unroll
  for (int i = 0; i < 4; ++i)
#pragma unroll
    for (int j = 0; j < 2; ++j) acc[i][j] = (f32x4){0.f, 0.f, 0.f, 0.f};

  const int lkc = lane >> 4, li = lane & 15;
  for (int k0 = kb; k0 < kb + KS; k0 += 32) {
#pragma unroll
    for (int it = 0; it < 2; ++it) {
      int s = it * 256 + tid;        // 0..511 A slots
      int kc = s >> 7, r = s & 127;
      __builtin_amdgcn_global_load_lds(
          (const __attribute__((address_space(1))) void*)(A + (size_t)(row0 + r) * lda + k0 + kc * 8),
          (__attribute__((address_space(3))) void*)(&As[s * 8]), 16, 0, 0);
    }
    {
      int s = tid;                   // 0..255 B slots
      int kc = s >> 6, r = s & 63;
      __builtin_amdgcn_global_load_lds(
          (const __attribute__((address_space(1))) void*)(Bt + (size_t)(col0 + r) * ldb + k0 + kc * 8),
          (__attribute__((address_space(3))) void*)(&Bs[s * 8]), 16, 0, 0);
    }
    __syncthreads();
    bf16x8 af[4], bfr[2];
#pragma unroll
    for (int mt = 0; mt < 4; ++mt)
      af[mt] = *(const bf16x8*)&As[(lkc * 128 + wm0 + mt * 16 + li) * 8];
#pragma unroll
    for (int nt = 0; nt < 2; ++nt)
      bfr[nt] = *(const bf16x8*)&Bs[(lkc * 64 + wn0 + nt * 16 + li) * 8];
#pragma unroll
    for (int mt = 0; mt < 4; ++mt)
#pragma unroll
      for (int nt = 0; nt < 2; ++nt)
        acc[mt][nt] = __builtin_amdgcn_mfma_f32_16x16x32_bf16(
            af[mt], bfr[nt], acc[mt][nt], 0, 0, 0);
    __syncthreads();
  }
  // C/D layout: col=lane&15, row=(lane>>4)*4+reg (m89-verified)
  const int lq = lane >> 4;
  const size_t zoff = (size_t)blockIdx.z * zstride;
#pragma unroll
  for (int mt = 0; mt < 4; ++mt) {
    int gm0 = row0 + wm0 + mt * 16 + lq * 4;
#pragma unroll
    for (int nt = 0; nt < 2; ++nt) {
      int gn = col0 + wn0 + nt * 16 + li;
      float* Cp; int ld, cn;
      if (gn < N1) { Cp = C1; ld = ld1; cn = gn; }
      else         { Cp = C2; ld = ld2; cn = gn - N1; }
#pragma unroll
      for (int r = 0; r < 4; ++r)
        Cp[zoff + (size_t)(gm0 + r) * ld + cn] = acc[mt][nt][r];
    }
  }
}

// ---------------------------------------------------------------------------
// Split-K reduce for out_proj: out[i] = P0[i] + P1[i], float4.
// ---------------------------------------------------------------------------
__global__ __launch_bounds__(256) void splitk_reduce2(
    const float* __restrict__ P, float* __restrict__ out, int n4, size_t zstride) {
  int i = blockIdx.x * 256 + threadIdx.x;
  if (i >= n4) return;
  float4 a = ((const float4*)P)[i];
  float4 b = ((const float4*)(P + zstride))[i];
  ((float4*)out)[i] = make_float4(a.x + b.x, a.y + b.y, a.z + b.z, a.w + b.w);
}

// ---------------------------------------------------------------------------
// Depthwise causal conv (width 4) + bias + SiLU -> bf16 U.
// ---------------------------------------------------------------------------
__global__ __launch_bounds__(256) void conv_silu(
    const float* __restrict__ UPRE, const float* __restrict__ cw,
    const float* __restrict__ cb, unsigned short* __restrict__ UB) {
  int idx = blockIdx.x * 256 + threadIdx.x;
  int d = idx & (DINNER - 1);
  int l = (idx >> 11) & (LSEQ - 1);
  int b = idx >> 21;
  float acc = cb[d];
#pragma unroll
  for (int k = 0; k < DCONV; ++k) {
    int ll = l + k - (DCONV - 1);
    if (ll >= 0)
      acc += UPRE[((size_t)(b * LSEQ + ll)) * DINNER + d] * cw[d * DCONV + k];
  }
  UB[idx] = f2bf(acc / (1.f + __expf(-acc)));
}

// ---------------------------------------------------------------------------
// x_proj split-K: partial C[64 rows][32 cols] over K-slice of 256.
// ---------------------------------------------------------------------------
__global__ __launch_bounds__(256) void xproj_partial(
    const unsigned short* __restrict__ UB, const float* __restrict__ W,
    float* __restrict__ XPART) {
  const int ks = blockIdx.x;
  const int row0 = blockIdx.y * 64;
  const int kbase = ks * 256;
  __shared__ float Av[16][68];
  __shared__ float Bv[16][32];
  const int tid = threadIdx.x;
  const int col = tid & 31, rg = tid >> 5;
  float acc[8] = {};
  for (int kk = 0; kk < 256; kk += 16) {
#pragma unroll
    for (int i = 0; i < 4; ++i) {
      int e = tid + i * 256;
      int r = e >> 4, k = e & 15;
      Av[k][r] = bf2f(UB[(size_t)(row0 + r) * DINNER + kbase + kk + k]);
    }
#pragma unroll
    for (int i = 0; i < 2; ++i) {
      int e = tid + i * 256;
      int k = e >> 5, c = e & 31;
      Bv[k][c] = W[(size_t)(kbase + kk + k) * 32 + c];
    }
    __syncthreads();
#pragma unroll
    for (int k = 0; k < 16; ++k) {
      float b = Bv[k][col];
#pragma unroll
      for (int r = 0; r < 8; ++r) acc[r] += Av[k][rg * 8 + r] * b;
    }
    __syncthreads();
  }
#pragma unroll
  for (int r = 0; r < 8; ++r)
    XPART[(size_t)ks * NROWS * 32 + (size_t)(row0 + rg * 8 + r) * 32 + col] = acc[r];
}

__global__ __launch_bounds__(256) void xproj_reduce(
    const float* __restrict__ XPART, float* __restrict__ BC) {
  int i = blockIdx.x * 256 + threadIdx.x;
  float s = 0.f;
#pragma unroll
  for (int ks = 0; ks < 8; ++ks) s += XPART[(size_t)ks * NROWS * 32 + i];
  BC[i] = s;
}

// ---------------------------------------------------------------------------
// Scan pass 1: per-chunk decay product P and local state h (h0=0).
// ---------------------------------------------------------------------------
__global__ __launch_bounds__(256) void scan_pass1(
    const float* __restrict__ DELTA, const unsigned short* __restrict__ UB,
    const float* __restrict__ BC, const float* __restrict__ dt_b,
    const float* __restrict__ A_log,
    float* __restrict__ PBUF, float* __restrict__ HBUF) {
  const int bx = blockIdx.x;
  const int b = bx >> 8;
  const int c = (bx >> 3) & (NCHUNK - 1);
  const int d = ((bx & 7) << 8) + threadIdx.x;
  const int l0 = c * LCHUNK;
  __shared__ float sB[LCHUNK * DSTATE];
#pragma unroll
  for (int i = 0; i < 2; ++i) {
    int e = threadIdx.x + i * 256;
    sB[e] = BC[((size_t)(b * LSEQ + l0 + (e >> 4))) * 32 + (e & 15)];
  }
  float Avv[DSTATE];
#pragma unroll
  for (int n = 0; n < DSTATE; ++n) Avv[n] = -__expf(A_log[d * DSTATE + n]);
  const float dtb = dt_b[d];
  float h[DSTATE], P[DSTATE];
#pragma unroll
  for (int n = 0; n < DSTATE; ++n) { h[n] = 0.f; P[n] = 1.f; }
  __syncthreads();
  for (int lc = 0; lc < LCHUNK; ++lc) {
    size_t off = ((size_t)(b * LSEQ + l0 + lc)) * DINNER + d;
    float xp = DELTA[off] + dtb;
    float delta = (xp > 20.f) ? xp : __logf(1.f + __expf(xp));
    float du = delta * bf2f(UB[off]);
#pragma unroll
    for (int n = 0; n < DSTATE; ++n) {
      float dA = __expf(delta * Avv[n]);
      P[n] *= dA;
      h[n] = dA * h[n] + du * sB[lc * DSTATE + n];
    }
  }
  size_t base = ((size_t)(b * NCHUNK + c)) * DSTATE * DINNER + d;
#pragma unroll
  for (int n = 0; n < DSTATE; ++n) {
    PBUF[base + (size_t)n * DINNER] = P[n];
    HBUF[base + (size_t)n * DINNER] = h[n];
  }
}

// ---------------------------------------------------------------------------
// Scan combine: sequential prefix across 32 chunks per (b,n,d).
// ---------------------------------------------------------------------------
__global__ __launch_bounds__(256) void scan_combine(
    const float* __restrict__ PBUF, float* __restrict__ HBUF) {
  const int bx = blockIdx.x;
  const int b = bx >> 7;
  const int n = (bx >> 3) & (DSTATE - 1);
  const int d = ((bx & 7) << 8) + threadIdx.x;
  float h = 0.f;
  for (int c = 0; c < NCHUNK; ++c) {
    size_t idx = (((size_t)(b * NCHUNK + c)) * DSTATE + n) * DINNER + d;
    float p = PBUF[idx];
    float hl = HBUF[idx];
    HBUF[idx] = h;
    h = p * h + hl;
  }
}

// ---------------------------------------------------------------------------
// Scan pass 2: rescan from true incoming state; y = C.h + u*D, gated by
// silu(res); emit bf16 Y for the out_proj MFMA GEMM.
// ---------------------------------------------------------------------------
__global__ __launch_bounds__(256) void scan_pass2(
    const float* __restrict__ DELTA, const unsigned short* __restrict__ UB,
    const float* __restrict__ BC, const float* __restrict__ HBUF,
    const float* __restrict__ dt_b, const float* __restrict__ A_log,
    const float* __restrict__ D_param, const float* __restrict__ RES,
    unsigned short* __restrict__ YB) {
  const int bx = blockIdx.x;
  const int b = bx >> 8;
  const int c = (bx >> 3) & (NCHUNK - 1);
  const int d = ((bx & 7) << 8) + threadIdx.x;
  const int l0 = c * LCHUNK;
  __shared__ float sBC[LCHUNK * 32];
#pragma unroll
  for (int i = 0; i < 4; ++i) {
    int e = threadIdx.x + i * 256;
    sBC[e] = BC[((size_t)(b * LSEQ + l0 + (e >> 5))) * 32 + (e & 31)];
  }
  float Avv[DSTATE];
#pragma unroll
  for (int n = 0; n < DSTATE; ++n) Avv[n] = -__expf(A_log[d * DSTATE + n]);
  const float dtb = dt_b[d];
  const float Dp = D_param[d];
  float h[DSTATE];
  size_t base = ((size_t)(b * NCHUNK + c)) * DSTATE * DINNER + d;
#pragma unroll
  for (int n = 0; n < DSTATE; ++n) h[n] = HBUF[base + (size_t)n * DINNER];
  __syncthreads();
  for (int lc = 0; lc < LCHUNK; ++lc) {
    size_t off = ((size_t)(b * LSEQ + l0 + lc)) * DINNER + d;
    float xp = DELTA[off] + dtb;
    float delta = (xp > 20.f) ? xp : __logf(1.f + __expf(xp));
    float uu = bf2f(UB[off]);
    float du = delta * uu;
    float y = 0.f;
#pragma unroll
    for (int n = 0; n < DSTATE; ++n) {
      float dA = __expf(delta * Avv[n]);
      h[n] = dA * h[n] + du * sBC[lc * 32 + n];
      y += h[n] * sBC[lc * 32 + 16 + n];
    }
    y += uu * Dp;
    float r = RES[off];
    YB[off] = f2bf(y * (r / (1.f + __expf(-r))));
  }
}

// ---------------------------------------------------------------------------
extern "C" void kernel_launch(void* const* d_in, const int* in_sizes, int n_in,
                              void* d_out, int out_size, void* d_ws, size_t ws_size,
                              hipStream_t stream) {
  const float* x       = (const float*)d_in[0];
  const float* w_in    = (const float*)d_in[1];
  const float* conv_w  = (const float*)d_in[2];
  const float* conv_b  = (const float*)d_in[3];
  const float* xproj_w = (const float*)d_in[4];
  const float* dt_w    = (const float*)d_in[5];
  const float* dt_b    = (const float*)d_in[6];
  const float* A_log   = (const float*)d_in[7];
  const float* D_par   = (const float*)d_in[8];
  const float* out_w   = (const float*)d_in[9];
  float* out = (float*)d_out;

  char* ws = (char*)d_ws;
  const size_t MB = 1024 * 1024;
  float* UPRE  = (float*)(ws + 0 * MB);          // 16 MB; aliased by DELTA, then OPART
  float* RES   = (float*)(ws + 16 * MB);         // 16 MB
  float* DELTA = UPRE;
  unsigned short* UB   = (unsigned short*)(ws + 32 * MB);  // 8 MB
  unsigned short* YB   = (unsigned short*)(ws + 40 * MB);  // 8 MB
  unsigned short* XB   = (unsigned short*)(ws + 48 * MB);  // 4 MB (dead after in_proj)
  unsigned short* WINB = (unsigned short*)(ws + 52 * MB);  // 8 MB (dead after in_proj)
  unsigned short* DTWB = (unsigned short*)(ws + 60 * MB);  // 8 MB (dead after dt_proj)
  unsigned short* OWB  = (unsigned short*)(ws + 68 * MB);  // 4 MB (live to end)
  // overlays (first written after underlying buffer dies)
  float* PBUF  = (float*)(ws + 48 * MB);         // 8 MB over XB+WINB[lo]
  float* BCb   = (float*)(ws + 56 * MB);         // 256 KB over WINB[hi]
  float* XPART = (float*)(ws + 56 * MB + 512 * 1024);  // 2 MB over WINB[hi]
  float* HBUF  = (float*)(ws + 60 * MB);         // 8 MB over DTWB
  float* OPART = (float*)(ws + 0 * MB);          // 16 MB over UPRE/DELTA (dead after scan2)
  // footprint: 72 MB

  dim3 blk(256);
  // convert inputs to bf16 (weights transposed to [N][K])
  cvt_ew<<<dim3(NROWS * DMODEL / 1024), blk, 0, stream>>>(x, XB);
  cvt_tr<<<dim3(2 * DINNER / 32, DMODEL / 32), blk, 0, stream>>>(w_in, WINB, DMODEL, 2 * DINNER);
  cvt_ew<<<dim3(DINNER * DINNER / 1024), blk, 0, stream>>>(dt_w, DTWB);
  cvt_tr<<<dim3(DMODEL / 32, DINNER / 32), blk, 0, stream>>>(out_w, OWB, DINNER, DMODEL);
  // in_proj: XB(2048x1024) x WINB(4096x1024)^T -> [UPRE | RES]  (1024 blocks)
  mfma_gemm_nt<<<dim3(2 * DINNER / 64, NROWS / 128, 1), blk, 0, stream>>>(
      XB, DMODEL, WINB, DMODEL, UPRE, DINNER, RES, DINNER, DINNER, DMODEL, 0);
  // conv + silu -> UB bf16
  conv_silu<<<dim3(NROWS * DINNER / 256), blk, 0, stream>>>(UPRE, conv_w, conv_b, UB);
  // x_proj split-K -> BC
  xproj_partial<<<dim3(8, NROWS / 64), blk, 0, stream>>>(UB, xproj_w, XPART);
  xproj_reduce<<<dim3(NROWS * 32 / 256), blk, 0, stream>>>(XPART, BCb);
  // dt_proj: UB x DTWB^T -> DELTA  (512 blocks)
  mfma_gemm_nt<<<dim3(DINNER / 64, NROWS / 128, 1), blk, 0, stream>>>(
      UB, DINNER, DTWB, DINNER, DELTA, DINNER, DELTA, DINNER, DINNER, DINNER, 0);
  // chunked selective scan
  scan_pass1<<<dim3(BATCH * NCHUNK * (DINNER / 256)), blk, 0, stream>>>(
      DELTA, UB, BCb, dt_b, A_log, PBUF, HBUF);
  scan_combine<<<dim3(BATCH * DSTATE * (DINNER / 256)), blk, 0, stream>>>(PBUF, HBUF);
  scan_pass2<<<dim3(BATCH * NCHUNK * (DINNER / 256)), blk, 0, stream>>>(
      DELTA, UB, BCb, HBUF, dt_b, A_log, D_par, RES, YB);
  // out_proj: YB(2048x2048) x OWB(1024x2048)^T, split-K=2 -> OPART (512 blocks)
  const size_t ZS = (size_t)NROWS * DMODEL;   // 2M elements per slice
  mfma_gemm_nt<<<dim3(DMODEL / 64, NROWS / 128, 2), blk, 0, stream>>>(
      YB, DINNER, OWB, DINNER, OPART, DMODEL, OPART, DMODEL, DMODEL, DINNER / 2, ZS);
  splitk_reduce2<<<dim3(NROWS * DMODEL / 1024), blk, 0, stream>>>(
      OPART, out, NROWS * DMODEL / 4, ZS);
}

// Round 5
// 348.885 us; speedup vs baseline: 8.5969x; 1.0281x over previous
//
#include <hip/hip_runtime.h>
#include <math.h>

// Problem constants
#define BATCH   2
#define LSEQ    1024
#define DMODEL  1024
#define DSTATE  16
#define DCONV   4
#define DINNER  2048
#define NROWS   (BATCH * LSEQ)   // 2048

#define LCHUNK  32
#define NCHUNK  32

typedef short  bf16x8 __attribute__((ext_vector_type(8)));
typedef float  f32x4  __attribute__((ext_vector_type(4)));

__device__ __forceinline__ unsigned short f2bf(float f) {
  unsigned int u = __builtin_bit_cast(unsigned int, f);
  u = (u + 0x7fffu + ((u >> 16) & 1u)) >> 16;   // RNE
  return (unsigned short)u;
}
__device__ __forceinline__ float bf2f(unsigned short h) {
  return __builtin_bit_cast(float, (unsigned int)h << 16);
}

// ---------------------------------------------------------------------------
// fp32 -> bf16 elementwise (4 elems/thread)
// ---------------------------------------------------------------------------
__global__ __launch_bounds__(256) void cvt_ew(
    const float* __restrict__ s, unsigned short* __restrict__ d) {
  int i = blockIdx.x * 256 + threadIdx.x;
  float4 v = ((const float4*)s)[i];
  ushort4 o;
  o.x = f2bf(v.x); o.y = f2bf(v.y); o.z = f2bf(v.z); o.w = f2bf(v.w);
  ((ushort4*)d)[i] = o;
}

// ---------------------------------------------------------------------------
// fp32 [R][C] -> bf16 [C][R] transpose-convert. 32x32 LDS tile.
// ---------------------------------------------------------------------------
__global__ __launch_bounds__(256) void cvt_tr(
    const float* __restrict__ s, unsigned short* __restrict__ d, int R, int C) {
  __shared__ float T[32][33];
  const int c0 = blockIdx.x * 32, r0 = blockIdx.y * 32;
  const int tid = threadIdx.x;
#pragma unroll
  for (int i = 0; i < 4; ++i) {
    int e = tid + i * 256;
    int r = e >> 5, c = e & 31;
    T[r][c] = s[(size_t)(r0 + r) * C + c0 + c];
  }
  __syncthreads();
#pragma unroll
  for (int i = 0; i < 4; ++i) {
    int e = tid + i * 256;
    int c = e >> 5, r = e & 31;
    d[(size_t)(c0 + c) * R + r0 + r] = f2bf(T[r][c]);
  }
}

// ---------------------------------------------------------------------------
// bf16 MFMA GEMM (NT): 128(M) x 64(N) block, 4 waves (each 64x32 = 4x2 MFMAs
// of 16x16x32), BK=64, LDS 24 KB.
// XCD swizzle: linear block id -> xcd = id%8 (MI355X round-robin heuristic);
// XCD x owns M-row-panels {2x, 2x+1} across ALL column tiles, so its 4 MiB L2
// keeps the two A-panels (1 MB) resident while streaming B -> vmem re-fetch
// served from L2 (34.5 TB/s) instead of L3/HBM (~6.5 TB/s). Requires
// gridDim.y == 16 (all three GEMMs here). Pure tile permutation: correct
// regardless of the actual XCD mapping.
// Split-K via gridDim.z: slice z covers [z*KS,(z+1)*KS), out += z*zstride.
// Split-column epilogue: col < N1 -> C1 else C2 (BN=64 never straddles).
// ---------------------------------------------------------------------------
__global__ __launch_bounds__(256) void mfma_gemm_nt(
    const unsigned short* __restrict__ A, int lda,
    const unsigned short* __restrict__ Bt, int ldb,
    float* __restrict__ C1, int ld1,
    float* __restrict__ C2, int ld2, int N1,
    int KS, size_t zstride) {
  __shared__ unsigned short As[8 * 128 * 8];  // 16 KB  [kc 0..7][row 0..127][8]
  __shared__ unsigned short Bs[8 * 64 * 8];   //  8 KB  [kc 0..7][row 0..63][8]
  const int tid  = threadIdx.x;
  const int wave = tid >> 6;
  const int lane = tid & 63;
  // XCD-aware tile remap (gridDim.y must be 16)
  const int linear = blockIdx.y * gridDim.x + blockIdx.x;
  const int xcd = linear & 7;
  const int pos = linear >> 3;
  const int row0 = (xcd * 2 + (pos & 1)) * 128;
  const int col0 = (pos >> 1) * 64;
  const int wm0 = (wave >> 1) * 64;
  const int wn0 = (wave & 1) * 32;
  const int kb = blockIdx.z * KS;
  f32x4 acc[4][2];
#pragma unroll
  for (int i = 0; i < 4; ++i)
#pragma unroll
    for (int j = 0; j < 2; ++j) acc[i][j] = (f32x4){0.f, 0.f, 0.f, 0.f};

  const int lkc = lane >> 4, li = lane & 15;
  for (int k0 = kb; k0 < kb + KS; k0 += 64) {
#pragma unroll
    for (int it = 0; it < 4; ++it) {
      int s = it * 256 + tid;        // 0..1023 A slots
      int kc = s >> 7, r = s & 127;
      __builtin_amdgcn_global_load_lds(
          (const __attribute__((address_space(1))) void*)(A + (size_t)(row0 + r) * lda + k0 + kc * 8),
          (__attribute__((address_space(3))) void*)(&As[s * 8]), 16, 0, 0);
    }
#pragma unroll
    for (int it = 0; it < 2; ++it) {
      int s = it * 256 + tid;        // 0..511 B slots
      int kc = s >> 6, r = s & 63;
      __builtin_amdgcn_global_load_lds(
          (const __attribute__((address_space(1))) void*)(Bt + (size_t)(col0 + r) * ldb + k0 + kc * 8),
          (__attribute__((address_space(3))) void*)(&Bs[s * 8]), 16, 0, 0);
    }
    __syncthreads();
#pragma unroll
    for (int half = 0; half < 2; ++half) {
      bf16x8 af[4], bfr[2];
#pragma unroll
      for (int mt = 0; mt < 4; ++mt)
        af[mt] = *(const bf16x8*)&As[((half * 4 + lkc) * 128 + wm0 + mt * 16 + li) * 8];
#pragma unroll
      for (int nt = 0; nt < 2; ++nt)
        bfr[nt] = *(const bf16x8*)&Bs[((half * 4 + lkc) * 64 + wn0 + nt * 16 + li) * 8];
#pragma unroll
      for (int mt = 0; mt < 4; ++mt)
#pragma unroll
        for (int nt = 0; nt < 2; ++nt)
          acc[mt][nt] = __builtin_amdgcn_mfma_f32_16x16x32_bf16(
              af[mt], bfr[nt], acc[mt][nt], 0, 0, 0);
    }
    __syncthreads();
  }
  // C/D layout: col=lane&15, row=(lane>>4)*4+reg (m89-verified)
  const int lq = lane >> 4;
  const size_t zoff = (size_t)blockIdx.z * zstride;
#pragma unroll
  for (int mt = 0; mt < 4; ++mt) {
    int gm0 = row0 + wm0 + mt * 16 + lq * 4;
#pragma unroll
    for (int nt = 0; nt < 2; ++nt) {
      int gn = col0 + wn0 + nt * 16 + li;
      float* Cp; int ld, cn;
      if (gn < N1) { Cp = C1; ld = ld1; cn = gn; }
      else         { Cp = C2; ld = ld2; cn = gn - N1; }
#pragma unroll
      for (int r = 0; r < 4; ++r)
        Cp[zoff + (size_t)(gm0 + r) * ld + cn] = acc[mt][nt][r];
    }
  }
}

// ---------------------------------------------------------------------------
// Split-K reduce for out_proj: out[i] = P0[i] + P1[i], float4.
// ---------------------------------------------------------------------------
__global__ __launch_bounds__(256) void splitk_reduce2(
    const float* __restrict__ P, float* __restrict__ out, int n4, size_t zstride) {
  int i = blockIdx.x * 256 + threadIdx.x;
  if (i >= n4) return;
  float4 a = ((const float4*)P)[i];
  float4 b = ((const float4*)(P + zstride))[i];
  ((float4*)out)[i] = make_float4(a.x + b.x, a.y + b.y, a.z + b.z, a.w + b.w);
}

// ---------------------------------------------------------------------------
// Depthwise causal conv (width 4) + bias + SiLU -> bf16 U.
// ---------------------------------------------------------------------------
__global__ __launch_bounds__(256) void conv_silu(
    const float* __restrict__ UPRE, const float* __restrict__ cw,
    const float* __restrict__ cb, unsigned short* __restrict__ UB) {
  int idx = blockIdx.x * 256 + threadIdx.x;
  int d = idx & (DINNER - 1);
  int l = (idx >> 11) & (LSEQ - 1);
  int b = idx >> 21;
  float acc = cb[d];
#pragma unroll
  for (int k = 0; k < DCONV; ++k) {
    int ll = l + k - (DCONV - 1);
    if (ll >= 0)
      acc += UPRE[((size_t)(b * LSEQ + ll)) * DINNER + d] * cw[d * DCONV + k];
  }
  UB[idx] = f2bf(acc / (1.f + __expf(-acc)));
}

// ---------------------------------------------------------------------------
// x_proj split-K: partial C[64 rows][32 cols] over K-slice of 256.
// ---------------------------------------------------------------------------
__global__ __launch_bounds__(256) void xproj_partial(
    const unsigned short* __restrict__ UB, const float* __restrict__ W,
    float* __restrict__ XPART) {
  const int ks = blockIdx.x;
  const int row0 = blockIdx.y * 64;
  const int kbase = ks * 256;
  __shared__ float Av[16][68];
  __shared__ float Bv[16][32];
  const int tid = threadIdx.x;
  const int col = tid & 31, rg = tid >> 5;
  float acc[8] = {};
  for (int kk = 0; kk < 256; kk += 16) {
#pragma unroll
    for (int i = 0; i < 4; ++i) {
      int e = tid + i * 256;
      int r = e >> 4, k = e & 15;
      Av[k][r] = bf2f(UB[(size_t)(row0 + r) * DINNER + kbase + kk + k]);
    }
#pragma unroll
    for (int i = 0; i < 2; ++i) {
      int e = tid + i * 256;
      int k = e >> 5, c = e & 31;
      Bv[k][c] = W[(size_t)(kbase + kk + k) * 32 + c];
    }
    __syncthreads();
#pragma unroll
    for (int k = 0; k < 16; ++k) {
      float b = Bv[k][col];
#pragma unroll
      for (int r = 0; r < 8; ++r) acc[r] += Av[k][rg * 8 + r] * b;
    }
    __syncthreads();
  }
#pragma unroll
  for (int r = 0; r < 8; ++r)
    XPART[(size_t)ks * NROWS * 32 + (size_t)(row0 + rg * 8 + r) * 32 + col] = acc[r];
}

__global__ __launch_bounds__(256) void xproj_reduce(
    const float* __restrict__ XPART, float* __restrict__ BC) {
  int i = blockIdx.x * 256 + threadIdx.x;
  float s = 0.f;
#pragma unroll
  for (int ks = 0; ks < 8; ++ks) s += XPART[(size_t)ks * NROWS * 32 + i];
  BC[i] = s;
}

// ---------------------------------------------------------------------------
// Scan pass 1: per-chunk decay product P and local state h (h0=0).
// ---------------------------------------------------------------------------
__global__ __launch_bounds__(256) void scan_pass1(
    const float* __restrict__ DELTA, const unsigned short* __restrict__ UB,
    const float* __restrict__ BC, const float* __restrict__ dt_b,
    const float* __restrict__ A_log,
    float* __restrict__ PBUF, float* __restrict__ HBUF) {
  const int bx = blockIdx.x;
  const int b = bx >> 8;
  const int c = (bx >> 3) & (NCHUNK - 1);
  const int d = ((bx & 7) << 8) + threadIdx.x;
  const int l0 = c * LCHUNK;
  __shared__ float sB[LCHUNK * DSTATE];
#pragma unroll
  for (int i = 0; i < 2; ++i) {
    int e = threadIdx.x + i * 256;
    sB[e] = BC[((size_t)(b * LSEQ + l0 + (e >> 4))) * 32 + (e & 15)];
  }
  float Avv[DSTATE];
#pragma unroll
  for (int n = 0; n < DSTATE; ++n) Avv[n] = -__expf(A_log[d * DSTATE + n]);
  const float dtb = dt_b[d];
  float h[DSTATE], P[DSTATE];
#pragma unroll
  for (int n = 0; n < DSTATE; ++n) { h[n] = 0.f; P[n] = 1.f; }
  __syncthreads();
  for (int lc = 0; lc < LCHUNK; ++lc) {
    size_t off = ((size_t)(b * LSEQ + l0 + lc)) * DINNER + d;
    float xp = DELTA[off] + dtb;
    float delta = (xp > 20.f) ? xp : __logf(1.f + __expf(xp));
    float du = delta * bf2f(UB[off]);
#pragma unroll
    for (int n = 0; n < DSTATE; ++n) {
      float dA = __expf(delta * Avv[n]);
      P[n] *= dA;
      h[n] = dA * h[n] + du * sB[lc * DSTATE + n];
    }
  }
  size_t base = ((size_t)(b * NCHUNK + c)) * DSTATE * DINNER + d;
#pragma unroll
  for (int n = 0; n < DSTATE; ++n) {
    PBUF[base + (size_t)n * DINNER] = P[n];
    HBUF[base + (size_t)n * DINNER] = h[n];
  }
}

// ---------------------------------------------------------------------------
// Scan combine: sequential prefix across 32 chunks per (b,n,d).
// ---------------------------------------------------------------------------
__global__ __launch_bounds__(256) void scan_combine(
    const float* __restrict__ PBUF, float* __restrict__ HBUF) {
  const int bx = blockIdx.x;
  const int b = bx >> 7;
  const int n = (bx >> 3) & (DSTATE - 1);
  const int d = ((bx & 7) << 8) + threadIdx.x;
  float h = 0.f;
  for (int c = 0; c < NCHUNK; ++c) {
    size_t idx = (((size_t)(b * NCHUNK + c)) * DSTATE + n) * DINNER + d;
    float p = PBUF[idx];
    float hl = HBUF[idx];
    HBUF[idx] = h;
    h = p * h + hl;
  }
}

// ---------------------------------------------------------------------------
// Scan pass 2: rescan from true incoming state; y = C.h + u*D, gated by
// silu(res); emit bf16 Y for the out_proj MFMA GEMM.
// ---------------------------------------------------------------------------
__global__ __launch_bounds__(256) void scan_pass2(
    const float* __restrict__ DELTA, const unsigned short* __restrict__ UB,
    const float* __restrict__ BC, const float* __restrict__ HBUF,
    const float* __restrict__ dt_b, const float* __restrict__ A_log,
    const float* __restrict__ D_param, const float* __restrict__ RES,
    unsigned short* __restrict__ YB) {
  const int bx = blockIdx.x;
  const int b = bx >> 8;
  const int c = (bx >> 3) & (NCHUNK - 1);
  const int d = ((bx & 7) << 8) + threadIdx.x;
  const int l0 = c * LCHUNK;
  __shared__ float sBC[LCHUNK * 32];
#pragma unroll
  for (int i = 0; i < 4; ++i) {
    int e = threadIdx.x + i * 256;
    sBC[e] = BC[((size_t)(b * LSEQ + l0 + (e >> 5))) * 32 + (e & 31)];
  }
  float Avv[DSTATE];
#pragma unroll
  for (int n = 0; n < DSTATE; ++n) Avv[n] = -__expf(A_log[d * DSTATE + n]);
  const float dtb = dt_b[d];
  const float Dp = D_param[d];
  float h[DSTATE];
  size_t base = ((size_t)(b * NCHUNK + c)) * DSTATE * DINNER + d;
#pragma unroll
  for (int n = 0; n < DSTATE; ++n) h[n] = HBUF[base + (size_t)n * DINNER];
  __syncthreads();
  for (int lc = 0; lc < LCHUNK; ++lc) {
    size_t off = ((size_t)(b * LSEQ + l0 + lc)) * DINNER + d;
    float xp = DELTA[off] + dtb;
    float delta = (xp > 20.f) ? xp : __logf(1.f + __expf(xp));
    float uu = bf2f(UB[off]);
    float du = delta * uu;
    float y = 0.f;
#pragma unroll
    for (int n = 0; n < DSTATE; ++n) {
      float dA = __expf(delta * Avv[n]);
      h[n] = dA * h[n] + du * sBC[lc * 32 + n];
      y += h[n] * sBC[lc * 32 + 16 + n];
    }
    y += uu * Dp;
    float r = RES[off];
    YB[off] = f2bf(y * (r / (1.f + __expf(-r))));
  }
}

// ---------------------------------------------------------------------------
extern "C" void kernel_launch(void* const* d_in, const int* in_sizes, int n_in,
                              void* d_out, int out_size, void* d_ws, size_t ws_size,
                              hipStream_t stream) {
  const float* x       = (const float*)d_in[0];
  const float* w_in    = (const float*)d_in[1];
  const float* conv_w  = (const float*)d_in[2];
  const float* conv_b  = (const float*)d_in[3];
  const float* xproj_w = (const float*)d_in[4];
  const float* dt_w    = (const float*)d_in[5];
  const float* dt_b    = (const float*)d_in[6];
  const float* A_log   = (const float*)d_in[7];
  const float* D_par   = (const float*)d_in[8];
  const float* out_w   = (const float*)d_in[9];
  float* out = (float*)d_out;

  char* ws = (char*)d_ws;
  const size_t MB = 1024 * 1024;
  float* UPRE  = (float*)(ws + 0 * MB);          // 16 MB; aliased by DELTA, then OPART
  float* RES   = (float*)(ws + 16 * MB);         // 16 MB
  float* DELTA = UPRE;
  unsigned short* UB   = (unsigned short*)(ws + 32 * MB);  // 8 MB
  unsigned short* YB   = (unsigned short*)(ws + 40 * MB);  // 8 MB
  unsigned short* XB   = (unsigned short*)(ws + 48 * MB);  // 4 MB (dead after in_proj)
  unsigned short* WINB = (unsigned short*)(ws + 52 * MB);  // 8 MB (dead after in_proj)
  unsigned short* DTWB = (unsigned short*)(ws + 60 * MB);  // 8 MB (dead after dt_proj)
  unsigned short* OWB  = (unsigned short*)(ws + 68 * MB);  // 4 MB (live to end)
  // overlays (first written after underlying buffer dies)
  float* PBUF  = (float*)(ws + 48 * MB);         // 8 MB over XB+WINB[lo]
  float* BCb   = (float*)(ws + 56 * MB);         // 256 KB over WINB[hi]
  float* XPART = (float*)(ws + 56 * MB + 512 * 1024);  // 2 MB over WINB[hi]
  float* HBUF  = (float*)(ws + 60 * MB);         // 8 MB over DTWB
  float* OPART = (float*)(ws + 0 * MB);          // 16 MB over UPRE/DELTA (dead after scan2)
  // footprint: 72 MB

  dim3 blk(256);
  // convert inputs to bf16 (weights transposed to [N][K])
  cvt_ew<<<dim3(NROWS * DMODEL / 1024), blk, 0, stream>>>(x, XB);
  cvt_tr<<<dim3(2 * DINNER / 32, DMODEL / 32), blk, 0, stream>>>(w_in, WINB, DMODEL, 2 * DINNER);
  cvt_ew<<<dim3(DINNER * DINNER / 1024), blk, 0, stream>>>(dt_w, DTWB);
  cvt_tr<<<dim3(DMODEL / 32, DINNER / 32), blk, 0, stream>>>(out_w, OWB, DINNER, DMODEL);
  // in_proj: XB(2048x1024) x WINB(4096x1024)^T -> [UPRE | RES]  (1024 blocks)
  mfma_gemm_nt<<<dim3(2 * DINNER / 64, NROWS / 128, 1), blk, 0, stream>>>(
      XB, DMODEL, WINB, DMODEL, UPRE, DINNER, RES, DINNER, DINNER, DMODEL, 0);
  // conv + silu -> UB bf16
  conv_silu<<<dim3(NROWS * DINNER / 256), blk, 0, stream>>>(UPRE, conv_w, conv_b, UB);
  // x_proj split-K -> BC
  xproj_partial<<<dim3(8, NROWS / 64), blk, 0, stream>>>(UB, xproj_w, XPART);
  xproj_reduce<<<dim3(NROWS * 32 / 256), blk, 0, stream>>>(XPART, BCb);
  // dt_proj: UB x DTWB^T -> DELTA  (512 blocks)
  mfma_gemm_nt<<<dim3(DINNER / 64, NROWS / 128, 1), blk, 0, stream>>>(
      UB, DINNER, DTWB, DINNER, DELTA, DINNER, DELTA, DINNER, DINNER, DINNER, 0);
  // chunked selective scan
  scan_pass1<<<dim3(BATCH * NCHUNK * (DINNER / 256)), blk, 0, stream>>>(
      DELTA, UB, BCb, dt_b, A_log, PBUF, HBUF);
  scan_combine<<<dim3(BATCH * DSTATE * (DINNER / 256)), blk, 0, stream>>>(PBUF, HBUF);
  scan_pass2<<<dim3(BATCH * NCHUNK * (DINNER / 256)), blk, 0, stream>>>(
      DELTA, UB, BCb, HBUF, dt_b, A_log, D_par, RES, YB);
  // out_proj: YB(2048x2048) x OWB(1024x2048)^T, split-K=2 -> OPART (512 blocks)
  const size_t ZS = (size_t)NROWS * DMODEL;   // 2M elements per slice
  mfma_gemm_nt<<<dim3(DMODEL / 64, NROWS / 128, 2), blk, 0, stream>>>(
      YB, DINNER, OWB, DINNER, OPART, DMODEL, OPART, DMODEL, DMODEL, DINNER / 2, ZS);
  splitk_reduce2<<<dim3(NROWS * DMODEL / 1024), blk, 0, stream>>>(
      OPART, out, NROWS * DMODEL / 4, ZS);
}